// Round 1
// baseline (77.238 us; speedup 1.0000x reference)
//
#include <hip/hip_runtime.h>
#include <hip/hip_bf16.h>

// Problem constants
#define P_ROWS   1024
#define N_IN     784
#define N_OUT    128
#define M_ROWS   785                 // N_IN + 1 (bias row)

// RATIO = G_MIN/(G_MAX-G_MIN);  L_AVG = log2(n_avg), n_avg = 2.132
#define RATIO_F  ((float)((1.0/983.3) / ((1.0/281.3) - (1.0/983.3))))
#define L_AVG_F  1.0922076f
#define LN2_F    0.6931472f

// GEMM shape: K = m-rows * 4 Taylor terms. 11 chunks of 72 m-rows (288 K).
// (chunk 10 covers m=720..791; m>=785 handled only in its step s=8 tail)
#define NCHK   11
#define MCH    72
#define NSTEP  9                     // 288 K / 32
#define NB_MAIN (64 * NCHK)          // 64 p-blocks x 11 chunks = 704 (~2.75/CU)

#define NB_MAX 64                    // K1 blocks / max partials

typedef _Float16 half8 __attribute__((ext_vector_type(8)));
typedef float    f32x4 __attribute__((ext_vector_type(4)));

// ---------------------------------------------------------------------------
// K1: per-block max|w| partials over {wp,wn,bp,bn} -> partial[0..63],
//     PLUS zero out[] (each block zeroes an 8 KB slice); out is fully
//     rewritten here before the main kernel accumulates atomically.
__global__ __launch_bounds__(256) void max_reduce_zero(
        const float* __restrict__ wp, const float* __restrict__ wn,
        const float* __restrict__ bp, const float* __restrict__ bn,
        float* __restrict__ partial, float4* __restrict__ out4) {
    const int b = blockIdx.x, t = threadIdx.x;

    // zero this block's slice of out: 64 blocks x 512 float4 = 131072 floats
    const float4 z = make_float4(0.f, 0.f, 0.f, 0.f);
    #pragma unroll
    for (int i = 0; i < 2; ++i)
        out4[(size_t)b * 512 + i * 256 + t] = z;

    const int nW4 = (N_IN * N_OUT) / 4;          // 25088
    const float4* wp4 = (const float4*)wp;
    const float4* wn4 = (const float4*)wn;
    int gid = b * 256 + t;                       // 0..16383
    float v = 0.0f;
    if (gid < N_OUT / 4) {
        float4 a = ((const float4*)bp)[gid], c = ((const float4*)bn)[gid];
        v = fmaxf(fmaxf(fmaxf(fabsf(a.x), fabsf(a.y)), fmaxf(fabsf(a.z), fabsf(a.w))),
                  fmaxf(fmaxf(fabsf(c.x), fabsf(c.y)), fmaxf(fabsf(c.z), fabsf(c.w))));
    }
    for (int i = gid; i < nW4; i += NB_MAX * 256) {
        float4 a = wp4[i], c = wn4[i];
        v = fmaxf(v, fmaxf(fmaxf(fabsf(a.x), fabsf(a.y)), fmaxf(fabsf(a.z), fabsf(a.w))));
        v = fmaxf(v, fmaxf(fmaxf(fabsf(c.x), fabsf(c.y)), fmaxf(fabsf(c.z), fabsf(c.w))));
    }
    for (int off = 32; off > 0; off >>= 1)
        v = fmaxf(v, __shfl_down(v, off, 64));
    __shared__ float smax[4];
    if ((t & 63) == 0) smax[t >> 6] = v;
    __syncthreads();
    if (t == 0)
        partial[b] = fmaxf(fmaxf(smax[0], smax[1]), fmaxf(smax[2], smax[3]));
}

// ---------------------------------------------------------------------------
// On-the-fly Taylor coefficients C_0..C_3 for weight row m, column n.
//   C_0 = 0.5(wp-wn); C_j = (Ap*Dp^j - An*Dn^j)/j!, A = c0 + 0.5w,
//   D = ln(n_param/n_avg).  (Identical expressions to the old precompute_c,
//   so the f16 fragments are bitwise the same.)
__device__ __forceinline__ void genB(int m, int n, float c0,
        const float* __restrict__ wp, const float* __restrict__ wn,
        const float* __restrict__ npar, float C[4]) {
    float wpv = wp[(size_t)m * N_OUT + n];
    float wnv = wn[(size_t)m * N_OUT + n];
    float2 nv = *(const float2*)(npar + (size_t)m * (2 * N_OUT) + 2 * n);
    float Dp = LN2_F * (__builtin_amdgcn_logf(nv.x) - L_AVG_F);
    float Dn = LN2_F * (__builtin_amdgcn_logf(nv.y) - L_AVG_F);
    float Ap = c0 + 0.5f * wpv;
    float An = c0 + 0.5f * wnv;
    float ApD = Ap * Dp,    AnD = An * Dn;
    float ApD2 = ApD * Dp,  AnD2 = AnD * Dn;
    float ApD3 = ApD2 * Dp, AnD3 = AnD2 * Dn;
    C[0] = Ap - An;                              // c0 cancels
    C[1] = ApD - AnD;
    C[2] = (ApD2 - AnD2) * 0.5f;
    C[3] = (ApD3 - AnD3) * (1.0f / 6.0f);
}

// Bias row (m == N_IN): weights come from bp/bn.
__device__ __forceinline__ void genBias(int n, float c0,
        const float* __restrict__ bp, const float* __restrict__ bn,
        const float* __restrict__ npar, float C[4]) {
    float wpv = bp[n];
    float wnv = bn[n];
    float2 nv = *(const float2*)(npar + (size_t)N_IN * (2 * N_OUT) + 2 * n);
    float Dp = LN2_F * (__builtin_amdgcn_logf(nv.x) - L_AVG_F);
    float Dn = LN2_F * (__builtin_amdgcn_logf(nv.y) - L_AVG_F);
    float Ap = c0 + 0.5f * wpv;
    float An = c0 + 0.5f * wnv;
    float ApD = Ap * Dp,    AnD = An * Dn;
    float ApD2 = ApD * Dp,  AnD2 = AnD * Dn;
    float ApD3 = ApD2 * Dp, AnD3 = AnD2 * Dn;
    C[0] = Ap - An;
    C[1] = ApD - AnD;
    C[2] = (ApD2 - AnD2) * 0.5f;
    C[3] = (ApD3 - AnD3) * (1.0f / 6.0f);
}

// ---------------------------------------------------------------------------
// Main fused kernel: MFMA micro-GEMM with on-the-fly B generation.
// 704 blocks (64 p-blocks x 11 chunks), 256 thr. F (A-operand) built in LDS
// in fragment order [sq][p] half8 (unchanged). B-fragments (Taylor coeffs)
// are generated in registers: each lane's 36 (m,n) pairs tile the block's
// 72x128 chunk exactly once, so there is NO intra-block redundancy — the
// old precompute_c kernel and its Cr workspace round-trip are deleted.
// Epilogue: unsafeAtomicAdd into out (zeroed by K1; 11 adds/output).
__global__ __launch_bounds__(256, 3) void memristor_main(
        const float* __restrict__ x,
        const float* __restrict__ wp, const float* __restrict__ wn,
        const float* __restrict__ bp, const float* __restrict__ bn,
        const float* __restrict__ npar, const float* __restrict__ partial,
        float* __restrict__ out) {
    const int bid = blockIdx.x;
    const int ch  = bid % NCHK;
    const int pb  = bid / NCHK;
    const int p0  = pb * 16;
    const int m0  = ch * MCH;
    const int t   = threadIdx.x;

    // global max|w| from the 64 partials (uniform -> scalar loads, L2-hot)
    float mw = 0.0f;
    #pragma unroll
    for (int i = 0; i < NB_MAX; ++i) mw = fmaxf(mw, partial[i]);
    const float c0 = 0.5f * RATIO_F * mw;

    // ---- stage F (A-operand) in LDS, fragment order [sq][p] ----
    __shared__ half8 F_lds[36 * 16];               // 9216 B
    const int NF4 = MCH / 4;                       // 18 float4 per row
    for (int idx = t; idx < 16 * NF4; idx += 256) {
        const int p     = idx / NF4;
        const int f4    = idx - p * NF4;
        const int mbase = m0 + f4 * 4;
        float xv[4];
        if (mbase + 3 < N_IN) {
            float4 v = *(const float4*)(x + (size_t)(p0 + p) * N_IN + mbase);
            xv[0] = v.x; xv[1] = v.y; xv[2] = v.z; xv[3] = v.w;
        } else {
            #pragma unroll
            for (int u = 0; u < 4; ++u) {
                int m = mbase + u;
                xv[u] = (m < N_IN) ? x[(size_t)(p0 + p) * N_IN + m] : -1.0f;
            }
        }
        #pragma unroll
        for (int u = 0; u < 4; ++u) {
            const int m  = mbase + u;
            const int ml = m - m0;
            float e;
            if (m < N_IN)
                e = (xv[u] > 0.0f) ? __builtin_amdgcn_logf(2.0f * xv[u]) : -1.0e4f;
            else
                e = (m == N_IN) ? 1.0f : -1.0e4f;  // bias row; pads -> F = 0
            float F0 = __builtin_amdgcn_exp2f(e * L_AVG_F);
            float F1 = F0 * e, F2 = F1 * e, F3 = F2 * e;
            _Float16* dst = (_Float16*)&F_lds[(ml >> 1) * 16 + p] + (ml & 1) * 4;
            dst[0] = (_Float16)F0;
            dst[1] = (_Float16)F1;
            dst[2] = (_Float16)F2;
            dst[3] = (_Float16)F3;
        }
    }
    __syncthreads();

    const int lane = t & 63;
    const int w    = t >> 6;
    const int quad = lane >> 4;
    const int col  = lane & 15;
    const int n0   = w * 32;                       // wave covers n0..n0+31
    const int nA   = n0 + col;
    const int nB   = n0 + 16 + col;
    const int mq   = m0 + quad * 2;                // lane's base m

    f32x4 acc0 = {0.f, 0.f, 0.f, 0.f};
    f32x4 acc1 = {0.f, 0.f, 0.f, 0.f};
    #pragma unroll
    for (int s = 0; s < NSTEP; ++s) {
        half8 a = F_lds[(s * 4 + quad) * 16 + col];                    // ds_read_b128
        half8 b0, b1;
        if (s < 8 || ch != NCHK - 1) {
            // all rows are plain weight rows (m <= 783): no guards needed
            #pragma unroll
            for (int bb = 0; bb < 2; ++bb) {
                const int m = mq + s * 8 + bb;
                float CA[4], CB[4];
                genB(m, nA, c0, wp, wn, npar, CA);
                genB(m, nB, c0, wp, wn, npar, CB);
                #pragma unroll
                for (int j = 0; j < 4; ++j) {
                    b0[bb * 4 + j] = (_Float16)CA[j];
                    b1[bb * 4 + j] = (_Float16)CB[j];
                }
            }
        } else {
            // chunk 10, step 8: m = 784..791. Only m==784 (quad 0, bb 0)
            // is real (bias row); the rest are zero-pads.
            #pragma unroll
            for (int j = 0; j < 8; ++j) { b0[j] = (_Float16)0.f; b1[j] = (_Float16)0.f; }
            if (quad == 0) {
                float CA[4], CB[4];
                genBias(nA, c0, bp, bn, npar, CA);
                genBias(nB, c0, bp, bn, npar, CB);
                #pragma unroll
                for (int j = 0; j < 4; ++j) {
                    b0[j] = (_Float16)CA[j];
                    b1[j] = (_Float16)CB[j];
                }
            }
        }
        acc0 = __builtin_amdgcn_mfma_f32_16x16x32_f16(a, b0, acc0, 0, 0, 0);
        acc1 = __builtin_amdgcn_mfma_f32_16x16x32_f16(a, b1, acc1, 0, 0, 0);
    }

    // D layout: row = quad*4 + r, col = lane&15. 8 coalesced f32 atomics/lane.
    float* obase = out + (size_t)(p0 + quad * 4) * N_OUT;
    #pragma unroll
    for (int r = 0; r < 4; ++r) {
        unsafeAtomicAdd(&obase[(size_t)r * N_OUT + n0 + col],      acc0[r]);
        unsafeAtomicAdd(&obase[(size_t)r * N_OUT + n0 + 16 + col], acc1[r]);
    }
}

// ---------------------------------------------------------------------------
extern "C" void kernel_launch(void* const* d_in, const int* in_sizes, int n_in,
                              void* d_out, int out_size, void* d_ws, size_t ws_size,
                              hipStream_t stream) {
    const float* x  = (const float*)d_in[0];
    const float* wp = (const float*)d_in[1];
    const float* wn = (const float*)d_in[2];
    const float* bp = (const float*)d_in[3];
    const float* bn = (const float*)d_in[4];
    const float* np = (const float*)d_in[5];
    float* out = (float*)d_out;

    float* partial = (float*)d_ws;                // 64 floats

    max_reduce_zero<<<NB_MAX, 256, 0, stream>>>(wp, wn, bp, bn, partial, (float4*)out);
    memristor_main<<<NB_MAIN, 256, 0, stream>>>(x, wp, wn, bp, bn, np, partial, out);
}